// Round 4
// baseline (842.410 us; speedup 1.0000x reference)
//
#include <hip/hip_runtime.h>

#define N_NODES 100000
#define N_EDGES 1600000
#define N_GRAPHS 1000
#define H 128
#define DEPTH 4
#define NB 391        // buckets of 256 nodes
#define BCAP 4864     // bucket capacity (mean 4096, sd 64 -> +12 sigma)

typedef __attribute__((ext_vector_type(8))) short bf16x8;
typedef __attribute__((ext_vector_type(4))) float f32x4;

__device__ __forceinline__ unsigned short f2bf(float f) {
  unsigned int u = __float_as_uint(f);
  u += 0x7FFF + ((u >> 16) & 1);
  return (unsigned short)(u >> 16);
}
__device__ __forceinline__ float bflo(unsigned int v) { return __uint_as_float(v << 16); }
__device__ __forceinline__ float bfhi(unsigned int v) { return __uint_as_float(v & 0xFFFF0000u); }

// ---------------- CSR build: two-level counting sort ----------------
__global__ __launch_bounds__(256) void k_bcnt(const int* __restrict__ dst, int* __restrict__ gcnt) {
  __shared__ int c[NB];
  int tid = threadIdx.x, e0 = blockIdx.x * 4096;
  for (int i = tid; i < NB; i += 256) c[i] = 0;
  __syncthreads();
#pragma unroll
  for (int i = 0; i < 16; ++i) {
    int e = e0 + i * 256 + tid;
    if (e < N_EDGES) atomicAdd(&c[dst[e] >> 8], 1);
  }
  __syncthreads();
  for (int i = tid; i < NB; i += 256)
    if (c[i]) atomicAdd(&gcnt[i], c[i]);
}

__global__ __launch_bounds__(512) void k_bscan(const int* __restrict__ gcnt, int* __restrict__ boff,
                                               int* __restrict__ cursor) {
  __shared__ int sh[512];
  int t = threadIdx.x;
  int v = (t < NB) ? gcnt[t] : 0;
  sh[t] = v;
  __syncthreads();
  for (int s = 1; s < 512; s <<= 1) {
    int x = (t >= s) ? sh[t - s] : 0;
    __syncthreads();
    sh[t] += x;
    __syncthreads();
  }
  if (t < NB) {
    int e = sh[t] - v;
    boff[t] = e;
    cursor[t] = e;
  }
  if (t == 0) boff[NB] = N_EDGES;
}

__global__ __launch_bounds__(256) void k_bucket(const int* __restrict__ src, const int* __restrict__ dst,
                                                int* __restrict__ cursor, unsigned int* __restrict__ ebuf) {
  __shared__ int cnt[NB];
  __shared__ int base[NB];
  int tid = threadIdx.x;
  int e0 = blockIdx.x * 4096;
  for (int i = tid; i < NB; i += 256) cnt[i] = 0;
  __syncthreads();
  unsigned int pk[16];
  int bk[16], rk[16];
#pragma unroll
  for (int i = 0; i < 16; ++i) {
    int e = e0 + i * 256 + tid;
    if (e < N_EDGES) {
      int s = src[e], d = dst[e];
      bk[i] = d >> 8;
      pk[i] = ((unsigned int)(d & 255) << 17) | (unsigned int)s;
      rk[i] = atomicAdd(&cnt[bk[i]], 1);
    } else
      bk[i] = -1;
  }
  __syncthreads();
  for (int i = tid; i < NB; i += 256)
    base[i] = cnt[i] ? atomicAdd(&cursor[i], cnt[i]) : 0;
  __syncthreads();
#pragma unroll
  for (int i = 0; i < 16; ++i)
    if (bk[i] >= 0) ebuf[base[bk[i]] + rk[i]] = pk[i];
}

__global__ __launch_bounds__(256) void k_bsort(const unsigned int* __restrict__ ebuf,
                                               const int* __restrict__ boff,
                                               int* __restrict__ csr, int* __restrict__ offs) {
  __shared__ unsigned int arr[BCAP];
  __shared__ unsigned int srt[BCAP];
  __shared__ unsigned short rnk[BCAP];
  __shared__ int cnt[256];
  __shared__ int off[257];
  int b = blockIdx.x, tid = threadIdx.x;
  int beg = boff[b], end = boff[b + 1];
  int ce = min(end - beg, BCAP);
  cnt[tid] = 0;
  __syncthreads();
  for (int i = tid; i < ce; i += 256) {
    unsigned int p = ebuf[beg + i];
    arr[i] = p;
    rnk[i] = (unsigned short)atomicAdd(&cnt[p >> 17], 1);
  }
  __syncthreads();
  int v = cnt[tid];
  off[tid + 1] = v;
  if (tid == 0) off[0] = 0;
  __syncthreads();
  for (int s = 1; s < 256; s <<= 1) {
    int x = (tid + 1 > s) ? off[tid + 1 - s] : 0;
    __syncthreads();
    off[tid + 1] += x;
    __syncthreads();
  }
  for (int i = tid; i < ce; i += 256) {
    unsigned int p = arr[i];
    srt[off[p >> 17] + rnk[i]] = p & 0x1FFFF;
  }
  __syncthreads();
  for (int i = tid; i < ce; i += 256) csr[beg + i] = (int)srt[i];
  int node = (b << 8) + tid;
  if (node < N_NODES) offs[node] = beg + off[tid];
  if (b == NB - 1 && tid == 0) offs[N_NODES] = N_EDGES;
}

// ---------------- stage W (fp32 KxN) transposed into LDS Wt[n][k] bf16, pad 136 ----------------
__device__ __forceinline__ void stage_w(const float* __restrict__ Wg, unsigned short* Wt, int tid) {
  for (int idx = tid; idx < 2048; idx += 256) {
    int ng4 = idx & 31, kp = idx >> 5;
    float4 r0 = *(const float4*)&Wg[(2 * kp) * H + 4 * ng4];
    float4 r1 = *(const float4*)&Wg[(2 * kp + 1) * H + 4 * ng4];
    unsigned int p0 = (unsigned int)f2bf(r0.x) | ((unsigned int)f2bf(r1.x) << 16);
    unsigned int p1 = (unsigned int)f2bf(r0.y) | ((unsigned int)f2bf(r1.y) << 16);
    unsigned int p2 = (unsigned int)f2bf(r0.z) | ((unsigned int)f2bf(r1.z) << 16);
    unsigned int p3 = (unsigned int)f2bf(r0.w) | ((unsigned int)f2bf(r1.w) << 16);
    *(unsigned int*)&Wt[(4 * ng4 + 0) * 136 + 2 * kp] = p0;
    *(unsigned int*)&Wt[(4 * ng4 + 1) * 136 + 2 * kp] = p1;
    *(unsigned int*)&Wt[(4 * ng4 + 2) * 136 + 2 * kp] = p2;
    *(unsigned int*)&Wt[(4 * ng4 + 3) * 136 + 2 * kp] = p3;
  }
}

// ---------------- Linear 0 (MFMA): h0 = relu(x @ W0 + b0), x fp32, h0 bf16 ----------------
__global__ __launch_bounds__(256) void k_lin(const float* __restrict__ in, const float* __restrict__ Wg,
                                             const float* __restrict__ bg, unsigned short* __restrict__ outp) {
  __shared__ unsigned short Wt[128 * 136];
  __shared__ unsigned short zs[64 * 136];
  int tid = threadIdx.x;
  int lane = tid & 63, w = tid >> 6;
  int q = lane >> 4, l16 = lane & 15;
  int n0 = blockIdx.x * 64;

  stage_w(Wg, Wt, tid);

  int row = n0 + w * 16 + l16;
  int rr = (row < N_NODES) ? row : 0;
  bf16x8 afrag[4];
#pragma unroll
  for (int ks = 0; ks < 4; ++ks) {
    const float* p = &in[(size_t)rr * H + ks * 32 + q * 8];
    float4 f0 = *(const float4*)p;
    float4 f1 = *(const float4*)(p + 4);
    bf16x8 a;
    a[0] = (short)f2bf(f0.x); a[1] = (short)f2bf(f0.y); a[2] = (short)f2bf(f0.z); a[3] = (short)f2bf(f0.w);
    a[4] = (short)f2bf(f1.x); a[5] = (short)f2bf(f1.y); a[6] = (short)f2bf(f1.z); a[7] = (short)f2bf(f1.w);
    afrag[ks] = a;
  }
  f32x4 acc[8];
#pragma unroll
  for (int ct = 0; ct < 8; ++ct) acc[ct] = (f32x4){0.f, 0.f, 0.f, 0.f};
  __syncthreads();
#pragma unroll
  for (int ct = 0; ct < 8; ++ct)
#pragma unroll
    for (int ks = 0; ks < 4; ++ks) {
      bf16x8 b = *(bf16x8*)&Wt[(ct * 16 + l16) * 136 + ks * 32 + q * 8];
      acc[ct] = __builtin_amdgcn_mfma_f32_16x16x32_bf16(afrag[ks], b, acc[ct], 0, 0, 0);
    }
#pragma unroll
  for (int ct = 0; ct < 8; ++ct) {
    float bb = bg[ct * 16 + l16];
#pragma unroll
    for (int r = 0; r < 4; ++r) {
      float v = fmaxf(acc[ct][r] + bb, 0.f);
      zs[(w * 16 + q * 4 + r) * 136 + ct * 16 + l16] = f2bf(v);
    }
  }
  __syncthreads();
  int node = tid >> 2, cb = (tid & 3) * 32;
  if (n0 + node < N_NODES) {
#pragma unroll
    for (int i = 0; i < 4; ++i) {
      uint4 v = *(uint4*)&zs[node * 136 + cb + i * 8];
      *(uint4*)&outp[(size_t)(n0 + node) * H + cb + i * 8] = v;
    }
  }
}

// ---------------- Fused agg + MLP: h_out = relu( relu((h+agg)@W1+b1)@W2 + b2 + h0 ) ----------------
__global__ __launch_bounds__(256) void k_agg_mlp(const unsigned short* __restrict__ hin,
                                                 const int* __restrict__ offs, const int* __restrict__ csr,
                                                 const float* __restrict__ W1g, const float* __restrict__ b1g,
                                                 const float* __restrict__ W2g, const float* __restrict__ b2g,
                                                 const unsigned short* __restrict__ h0,
                                                 unsigned short* __restrict__ hout) {
  __shared__ unsigned short Wt[128 * 136];
  __shared__ unsigned short zs[64 * 136];
  int tid = threadIdx.x;
  int lane = tid & 63, w = tid >> 6;
  int q = lane >> 4, l16 = lane & 15;
  int n0 = blockIdx.x * 64;

  stage_w(W1g, Wt, tid);

  // ---- gather phase: wave w aggregates its 16 rows into zs (wave-private) ----
  const unsigned int* hu = (const unsigned int*)hin;
  for (int m = 0; m < 16; ++m) {
    int node = n0 + w * 16 + m;
    if (node < N_NODES) {
      unsigned int self = hu[(size_t)node * 64 + lane];
      float sx = bflo(self), sy = bfhi(self);
      int beg = offs[node], end = offs[node + 1];
      for (int e = beg; e < end; e += 64) {
        int cnt = min(64, end - e);
        int idx = (lane < cnt) ? csr[e + lane] : 0;
        int j = 0;
        for (; j + 8 <= cnt; j += 8) {
          int s0 = __shfl(idx, j), s1 = __shfl(idx, j + 1), s2 = __shfl(idx, j + 2), s3 = __shfl(idx, j + 3);
          int s4 = __shfl(idx, j + 4), s5 = __shfl(idx, j + 5), s6 = __shfl(idx, j + 6), s7 = __shfl(idx, j + 7);
          unsigned int v0 = hu[(size_t)s0 * 64 + lane];
          unsigned int v1 = hu[(size_t)s1 * 64 + lane];
          unsigned int v2 = hu[(size_t)s2 * 64 + lane];
          unsigned int v3 = hu[(size_t)s3 * 64 + lane];
          unsigned int v4 = hu[(size_t)s4 * 64 + lane];
          unsigned int v5 = hu[(size_t)s5 * 64 + lane];
          unsigned int v6 = hu[(size_t)s6 * 64 + lane];
          unsigned int v7 = hu[(size_t)s7 * 64 + lane];
          sx += bflo(v0); sy += bfhi(v0);
          sx += bflo(v1); sy += bfhi(v1);
          sx += bflo(v2); sy += bfhi(v2);
          sx += bflo(v3); sy += bfhi(v3);
          sx += bflo(v4); sy += bfhi(v4);
          sx += bflo(v5); sy += bfhi(v5);
          sx += bflo(v6); sy += bfhi(v6);
          sx += bflo(v7); sy += bfhi(v7);
        }
        for (; j + 4 <= cnt; j += 4) {
          int s0 = __shfl(idx, j), s1 = __shfl(idx, j + 1), s2 = __shfl(idx, j + 2), s3 = __shfl(idx, j + 3);
          unsigned int v0 = hu[(size_t)s0 * 64 + lane];
          unsigned int v1 = hu[(size_t)s1 * 64 + lane];
          unsigned int v2 = hu[(size_t)s2 * 64 + lane];
          unsigned int v3 = hu[(size_t)s3 * 64 + lane];
          sx += bflo(v0); sy += bfhi(v0);
          sx += bflo(v1); sy += bfhi(v1);
          sx += bflo(v2); sy += bfhi(v2);
          sx += bflo(v3); sy += bfhi(v3);
        }
        for (; j < cnt; ++j) {
          int s = __shfl(idx, j);
          unsigned int v = hu[(size_t)s * 64 + lane];
          sx += bflo(v); sy += bfhi(v);
        }
      }
      unsigned int o = (unsigned int)f2bf(sx) | ((unsigned int)f2bf(sy) << 16);
      *(unsigned int*)&zs[(w * 16 + m) * 136 + 2 * lane] = o;
    }
  }
  // A-frags from zs (written by this same wave; LDS per-wave in-order)
  bf16x8 afrag[4];
#pragma unroll
  for (int ks = 0; ks < 4; ++ks)
    afrag[ks] = *(bf16x8*)&zs[(w * 16 + l16) * 136 + ks * 32 + q * 8];

  f32x4 acc[8];
#pragma unroll
  for (int ct = 0; ct < 8; ++ct) acc[ct] = (f32x4){0.f, 0.f, 0.f, 0.f};
  __syncthreads();  // Wt(W1) visible to all
#pragma unroll
  for (int ct = 0; ct < 8; ++ct)
#pragma unroll
    for (int ks = 0; ks < 4; ++ks) {
      bf16x8 b = *(bf16x8*)&Wt[(ct * 16 + l16) * 136 + ks * 32 + q * 8];
      acc[ct] = __builtin_amdgcn_mfma_f32_16x16x32_bf16(afrag[ks], b, acc[ct], 0, 0, 0);
    }
  __syncthreads();  // all waves done reading W1
  stage_w(W2g, Wt, tid);
#pragma unroll
  for (int ct = 0; ct < 8; ++ct) {
    float bb = b1g[ct * 16 + l16];
#pragma unroll
    for (int r = 0; r < 4; ++r) {
      float v = fmaxf(acc[ct][r] + bb, 0.f);
      zs[(w * 16 + q * 4 + r) * 136 + ct * 16 + l16] = f2bf(v);
    }
  }
  __syncthreads();  // Wt(W2) visible (zs rows stay wave-private)
  bf16x8 a2[4];
#pragma unroll
  for (int ks = 0; ks < 4; ++ks)
    a2[ks] = *(bf16x8*)&zs[(w * 16 + l16) * 136 + ks * 32 + q * 8];
  f32x4 acc2[8];
#pragma unroll
  for (int ct = 0; ct < 8; ++ct) acc2[ct] = (f32x4){0.f, 0.f, 0.f, 0.f};
#pragma unroll
  for (int ct = 0; ct < 8; ++ct)
#pragma unroll
    for (int ks = 0; ks < 4; ++ks) {
      bf16x8 b = *(bf16x8*)&Wt[(ct * 16 + l16) * 136 + ks * 32 + q * 8];
      acc2[ct] = __builtin_amdgcn_mfma_f32_16x16x32_bf16(a2[ks], b, acc2[ct], 0, 0, 0);
    }
#pragma unroll
  for (int ct = 0; ct < 8; ++ct) {
    float bb = b2g[ct * 16 + l16];
#pragma unroll
    for (int r = 0; r < 4; ++r) {
      float v = acc2[ct][r] + bb;
      zs[(w * 16 + q * 4 + r) * 136 + ct * 16 + l16] = f2bf(v);
    }
  }
  __syncthreads();  // epilogue reads zs cross-wave
  int node = tid >> 2, cb = (tid & 3) * 32;
  if (n0 + node < N_NODES) {
    size_t base = (size_t)(n0 + node) * H + cb;
#pragma unroll
    for (int i = 0; i < 4; ++i) {
      uint4 zv = *(uint4*)&zs[node * 136 + cb + i * 8];
      uint4 hv = *(const uint4*)&h0[base + i * 8];
      unsigned int zr[4] = {zv.x, zv.y, zv.z, zv.w};
      unsigned int hr[4] = {hv.x, hv.y, hv.z, hv.w};
      uint4 o;
      unsigned int orr[4];
#pragma unroll
      for (int j = 0; j < 4; ++j) {
        float a = fmaxf(bflo(zr[j]) + bflo(hr[j]), 0.f);
        float b = fmaxf(bfhi(zr[j]) + bfhi(hr[j]), 0.f);
        orr[j] = (unsigned int)f2bf(a) | ((unsigned int)f2bf(b) << 16);
      }
      o.x = orr[0]; o.y = orr[1]; o.z = orr[2]; o.w = orr[3];
      *(uint4*)&hout[base + i * 8] = o;
    }
  }
}

// ---------------- Pooling ----------------
__global__ void k_starts(const int* __restrict__ batch, int* __restrict__ starts) {
  int n = blockIdx.x * 256 + threadIdx.x;
  if (n >= N_NODES) return;
  int b = batch[n];
  if (n == 0) {
    for (int g = 0; g <= b; ++g) starts[g] = 0;
  } else {
    int bp = batch[n - 1];
    for (int g = bp + 1; g <= b; ++g) starts[g] = n;
  }
  if (n == N_NODES - 1) {
    for (int g = b + 1; g <= N_GRAPHS; ++g) starts[g] = N_NODES;
  }
}

__global__ __launch_bounds__(256) void k_pool(const unsigned short* __restrict__ h, const int* __restrict__ starts,
                                              const float* __restrict__ Wf, const float* __restrict__ bf_,
                                              float* __restrict__ out) {
  __shared__ float r[4];
  int g = blockIdx.x, tid = threadIdx.x;
  int lane = tid & 63, w = tid >> 6;
  int beg = starts[g], end = starts[g + 1];
  const unsigned int* hu = (const unsigned int*)h;
  float sx = 0.f, sy = 0.f;
  for (int n = beg + w; n < end; n += 4) {
    unsigned int v = hu[(size_t)n * 64 + lane];
    sx += bflo(v);
    sy += bfhi(v);
  }
  float val = sx * Wf[2 * lane] + sy * Wf[2 * lane + 1];
#pragma unroll
  for (int off = 32; off > 0; off >>= 1) val += __shfl_down(val, off);
  if (lane == 0) r[w] = val;
  __syncthreads();
  if (tid == 0) out[g] = r[0] + r[1] + r[2] + r[3] + bf_[0];
}

extern "C" void kernel_launch(void* const* d_in, const int* in_sizes, int n_in,
                              void* d_out, int out_size, void* d_ws, size_t ws_size,
                              hipStream_t stream) {
  const float* x = (const float*)d_in[0];
  const int* ei = (const int*)d_in[1];
  const int* srcv = ei;
  const int* dstv = ei + N_EDGES;
  const int* batch = (const int*)d_in[3];
  const float* W0 = (const float*)d_in[4];
  const float* b0 = (const float*)d_in[5];
  const float* W1 = (const float*)d_in[6];
  const float* b1 = (const float*)d_in[7];
  const float* W2 = (const float*)d_in[8];
  const float* b2 = (const float*)d_in[9];
  const float* Wf = (const float*)d_in[10];
  const float* bf_ = (const float*)d_in[11];
  float* out = (float*)d_out;

  char* ws = (char*)d_ws;
  size_t o = 0;
  auto alloc = [&](size_t bytes) {
    size_t r = o;
    o = (o + bytes + 255) & ~(size_t)255;
    return r;
  };
  int* offs = (int*)(ws + alloc((N_NODES + 1) * sizeof(int)));
  int* gcnt = (int*)(ws + alloc(NB * sizeof(int)));
  int* boff = (int*)(ws + alloc((NB + 1) * sizeof(int)));
  int* cursor = (int*)(ws + alloc(NB * sizeof(int)));
  unsigned int* ebuf = (unsigned int*)(ws + alloc((size_t)N_EDGES * 4));
  int* csr = (int*)(ws + alloc((size_t)N_EDGES * sizeof(int)));
  int* starts = (int*)(ws + alloc((N_GRAPHS + 1) * sizeof(int)));
  unsigned short* h0 = (unsigned short*)(ws + alloc((size_t)N_NODES * H * 2));
  unsigned short* hA = (unsigned short*)(ws + alloc((size_t)N_NODES * H * 2));
  unsigned short* hB = (unsigned short*)(ws + alloc((size_t)N_NODES * H * 2));

  hipMemsetAsync(gcnt, 0, NB * sizeof(int), stream);
  k_bcnt<<<NB, 256, 0, stream>>>(dstv, gcnt);
  k_bscan<<<1, 512, 0, stream>>>(gcnt, boff, cursor);
  k_bucket<<<NB, 256, 0, stream>>>(srcv, dstv, cursor, ebuf);
  k_bsort<<<NB, 256, 0, stream>>>(ebuf, boff, csr, offs);
  k_starts<<<(N_NODES + 255) / 256, 256, 0, stream>>>(batch, starts);

  const int nblk = (N_NODES + 63) / 64;
  k_lin<<<nblk, 256, 0, stream>>>(x, W0, b0, h0);
  const unsigned short* hin = h0;
  unsigned short* houts[2] = {hA, hB};
  for (int i = 0; i < DEPTH; ++i) {
    unsigned short* hout = houts[i & 1];
    k_agg_mlp<<<nblk, 256, 0, stream>>>(hin, offs, csr,
                                        W1 + (size_t)i * H * H, b1 + (size_t)i * H,
                                        W2 + (size_t)i * H * H, b2 + (size_t)i * H, h0, hout);
    hin = hout;
  }
  k_pool<<<N_GRAPHS, 256, 0, stream>>>(hin, starts, Wf, bf_, out);
}

// Round 5
// 671.842 us; speedup vs baseline: 1.2539x; 1.2539x over previous
//
#include <hip/hip_runtime.h>

#define N_NODES 100000
#define N_EDGES 1600000
#define N_GRAPHS 1000
#define H 128
#define DEPTH 4
#define NB 391        // buckets of 256 nodes
#define BCAP 4864     // bucket capacity (mean 4096, sd 64 -> +12 sigma)

typedef __attribute__((ext_vector_type(8))) short bf16x8;
typedef __attribute__((ext_vector_type(4))) float f32x4;

__device__ __forceinline__ unsigned short f2bf(float f) {
  unsigned int u = __float_as_uint(f);
  u += 0x7FFF + ((u >> 16) & 1);
  return (unsigned short)(u >> 16);
}
__device__ __forceinline__ float bflo(unsigned int v) { return __uint_as_float(v << 16); }
__device__ __forceinline__ float bfhi(unsigned int v) { return __uint_as_float(v & 0xFFFF0000u); }

// ---------------- CSR build: two-level counting sort ----------------
__global__ __launch_bounds__(256) void k_bcnt(const int* __restrict__ dst, int* __restrict__ gcnt) {
  __shared__ int c[NB];
  int tid = threadIdx.x, e0 = blockIdx.x * 4096;
  for (int i = tid; i < NB; i += 256) c[i] = 0;
  __syncthreads();
#pragma unroll
  for (int i = 0; i < 16; ++i) {
    int e = e0 + i * 256 + tid;
    if (e < N_EDGES) atomicAdd(&c[dst[e] >> 8], 1);
  }
  __syncthreads();
  for (int i = tid; i < NB; i += 256)
    if (c[i]) atomicAdd(&gcnt[i], c[i]);
}

__global__ __launch_bounds__(512) void k_bscan(const int* __restrict__ gcnt, int* __restrict__ boff,
                                               int* __restrict__ cursor) {
  __shared__ int sh[512];
  int t = threadIdx.x;
  int v = (t < NB) ? gcnt[t] : 0;
  sh[t] = v;
  __syncthreads();
  for (int s = 1; s < 512; s <<= 1) {
    int x = (t >= s) ? sh[t - s] : 0;
    __syncthreads();
    sh[t] += x;
    __syncthreads();
  }
  if (t < NB) {
    int e = sh[t] - v;
    boff[t] = e;
    cursor[t] = e;
  }
  if (t == 0) boff[NB] = N_EDGES;
}

__global__ __launch_bounds__(256) void k_bucket(const int* __restrict__ src, const int* __restrict__ dst,
                                                int* __restrict__ cursor, unsigned int* __restrict__ ebuf) {
  __shared__ int cnt[NB];
  __shared__ int base[NB];
  int tid = threadIdx.x;
  int e0 = blockIdx.x * 4096;
  for (int i = tid; i < NB; i += 256) cnt[i] = 0;
  __syncthreads();
  unsigned int pk[16];
  int bk[16], rk[16];
#pragma unroll
  for (int i = 0; i < 16; ++i) {
    int e = e0 + i * 256 + tid;
    if (e < N_EDGES) {
      int s = src[e], d = dst[e];
      bk[i] = d >> 8;
      pk[i] = ((unsigned int)(d & 255) << 17) | (unsigned int)s;
      rk[i] = atomicAdd(&cnt[bk[i]], 1);
    } else
      bk[i] = -1;
  }
  __syncthreads();
  for (int i = tid; i < NB; i += 256)
    base[i] = cnt[i] ? atomicAdd(&cursor[i], cnt[i]) : 0;
  __syncthreads();
#pragma unroll
  for (int i = 0; i < 16; ++i)
    if (bk[i] >= 0) ebuf[base[bk[i]] + rk[i]] = pk[i];
}

__global__ __launch_bounds__(256) void k_bsort(const unsigned int* __restrict__ ebuf,
                                               const int* __restrict__ boff,
                                               int* __restrict__ csr, int* __restrict__ offs) {
  __shared__ unsigned int arr[BCAP];
  __shared__ unsigned int srt[BCAP];
  __shared__ unsigned short rnk[BCAP];
  __shared__ int cnt[256];
  __shared__ int off[257];
  int b = blockIdx.x, tid = threadIdx.x;
  int beg = boff[b], end = boff[b + 1];
  int ce = min(end - beg, BCAP);
  cnt[tid] = 0;
  __syncthreads();
  for (int i = tid; i < ce; i += 256) {
    unsigned int p = ebuf[beg + i];
    arr[i] = p;
    rnk[i] = (unsigned short)atomicAdd(&cnt[p >> 17], 1);
  }
  __syncthreads();
  int v = cnt[tid];
  off[tid + 1] = v;
  if (tid == 0) off[0] = 0;
  __syncthreads();
  for (int s = 1; s < 256; s <<= 1) {
    int x = (tid + 1 > s) ? off[tid + 1 - s] : 0;
    __syncthreads();
    off[tid + 1] += x;
    __syncthreads();
  }
  for (int i = tid; i < ce; i += 256) {
    unsigned int p = arr[i];
    srt[off[p >> 17] + rnk[i]] = p & 0x1FFFF;
  }
  __syncthreads();
  for (int i = tid; i < ce; i += 256) csr[beg + i] = (int)srt[i];
  int node = (b << 8) + tid;
  if (node < N_NODES) offs[node] = beg + off[tid];
  if (b == NB - 1 && tid == 0) offs[N_NODES] = N_EDGES;
}

// ---------------- stage W (fp32 KxN) transposed into LDS Wt[n][k] bf16, pad 136 ----------------
__device__ __forceinline__ void stage_w(const float* __restrict__ Wg, unsigned short* Wt, int tid) {
  for (int idx = tid; idx < 2048; idx += 256) {
    int ng4 = idx & 31, kp = idx >> 5;
    float4 r0 = *(const float4*)&Wg[(2 * kp) * H + 4 * ng4];
    float4 r1 = *(const float4*)&Wg[(2 * kp + 1) * H + 4 * ng4];
    unsigned int p0 = (unsigned int)f2bf(r0.x) | ((unsigned int)f2bf(r1.x) << 16);
    unsigned int p1 = (unsigned int)f2bf(r0.y) | ((unsigned int)f2bf(r1.y) << 16);
    unsigned int p2 = (unsigned int)f2bf(r0.z) | ((unsigned int)f2bf(r1.z) << 16);
    unsigned int p3 = (unsigned int)f2bf(r0.w) | ((unsigned int)f2bf(r1.w) << 16);
    *(unsigned int*)&Wt[(4 * ng4 + 0) * 136 + 2 * kp] = p0;
    *(unsigned int*)&Wt[(4 * ng4 + 1) * 136 + 2 * kp] = p1;
    *(unsigned int*)&Wt[(4 * ng4 + 2) * 136 + 2 * kp] = p2;
    *(unsigned int*)&Wt[(4 * ng4 + 3) * 136 + 2 * kp] = p3;
  }
}

// ---------------- Linear 0 (MFMA): h0 = relu(x @ W0 + b0), x fp32, h0 bf16 ----------------
__global__ __launch_bounds__(256) void k_lin(const float* __restrict__ in, const float* __restrict__ Wg,
                                             const float* __restrict__ bg, unsigned short* __restrict__ outp) {
  __shared__ unsigned short Wt[128 * 136];
  __shared__ unsigned short zs[64 * 136];
  int tid = threadIdx.x;
  int lane = tid & 63, w = tid >> 6;
  int q = lane >> 4, l16 = lane & 15;
  int n0 = blockIdx.x * 64;

  stage_w(Wg, Wt, tid);

  int row = n0 + w * 16 + l16;
  int rr = (row < N_NODES) ? row : 0;
  bf16x8 afrag[4];
#pragma unroll
  for (int ks = 0; ks < 4; ++ks) {
    const float* p = &in[(size_t)rr * H + ks * 32 + q * 8];
    float4 f0 = *(const float4*)p;
    float4 f1 = *(const float4*)(p + 4);
    bf16x8 a;
    a[0] = (short)f2bf(f0.x); a[1] = (short)f2bf(f0.y); a[2] = (short)f2bf(f0.z); a[3] = (short)f2bf(f0.w);
    a[4] = (short)f2bf(f1.x); a[5] = (short)f2bf(f1.y); a[6] = (short)f2bf(f1.z); a[7] = (short)f2bf(f1.w);
    afrag[ks] = a;
  }
  f32x4 acc[8];
#pragma unroll
  for (int ct = 0; ct < 8; ++ct) acc[ct] = (f32x4){0.f, 0.f, 0.f, 0.f};
  __syncthreads();
#pragma unroll
  for (int ct = 0; ct < 8; ++ct)
#pragma unroll
    for (int ks = 0; ks < 4; ++ks) {
      bf16x8 b = *(bf16x8*)&Wt[(ct * 16 + l16) * 136 + ks * 32 + q * 8];
      acc[ct] = __builtin_amdgcn_mfma_f32_16x16x32_bf16(afrag[ks], b, acc[ct], 0, 0, 0);
    }
#pragma unroll
  for (int ct = 0; ct < 8; ++ct) {
    float bb = bg[ct * 16 + l16];
#pragma unroll
    for (int r = 0; r < 4; ++r) {
      float v = fmaxf(acc[ct][r] + bb, 0.f);
      zs[(w * 16 + q * 4 + r) * 136 + ct * 16 + l16] = f2bf(v);
    }
  }
  __syncthreads();
  int node = tid >> 2, cb = (tid & 3) * 32;
  if (n0 + node < N_NODES) {
#pragma unroll
    for (int i = 0; i < 4; ++i) {
      uint4 v = *(uint4*)&zs[node * 136 + cb + i * 8];
      *(uint4*)&outp[(size_t)(n0 + node) * H + cb + i * 8] = v;
    }
  }
}

// ---------------- Aggregation: half-wave per node, uint2/lane (512B per wave-load, 2 rows) ----------------
__global__ __launch_bounds__(256) void k_agg(const unsigned short* __restrict__ hin, const int* __restrict__ offs,
                                             const int* __restrict__ csr, unsigned short* __restrict__ zin) {
  int node = blockIdx.x * 8 + (threadIdx.x >> 5);
  int l = threadIdx.x & 31;
  if (node >= N_NODES) return;
  const uint2* hu = (const uint2*)hin;  // row = 32 uint2
  uint2 self = hu[(size_t)node * 32 + l];
  float a0 = bflo(self.x), a1 = bfhi(self.x), a2 = bflo(self.y), a3 = bfhi(self.y);
  int beg = offs[node], end = offs[node + 1];
  for (int e = beg; e < end; e += 32) {
    int cnt = min(32, end - e);
    int idx = (l < cnt) ? csr[e + l] : 0;
    int j = 0;
    for (; j + 8 <= cnt; j += 8) {
      int s0 = __shfl(idx, j, 32), s1 = __shfl(idx, j + 1, 32);
      int s2 = __shfl(idx, j + 2, 32), s3 = __shfl(idx, j + 3, 32);
      int s4 = __shfl(idx, j + 4, 32), s5 = __shfl(idx, j + 5, 32);
      int s6 = __shfl(idx, j + 6, 32), s7 = __shfl(idx, j + 7, 32);
      uint2 v0 = hu[(size_t)s0 * 32 + l];
      uint2 v1 = hu[(size_t)s1 * 32 + l];
      uint2 v2 = hu[(size_t)s2 * 32 + l];
      uint2 v3 = hu[(size_t)s3 * 32 + l];
      uint2 v4 = hu[(size_t)s4 * 32 + l];
      uint2 v5 = hu[(size_t)s5 * 32 + l];
      uint2 v6 = hu[(size_t)s6 * 32 + l];
      uint2 v7 = hu[(size_t)s7 * 32 + l];
      a0 += bflo(v0.x); a1 += bfhi(v0.x); a2 += bflo(v0.y); a3 += bfhi(v0.y);
      a0 += bflo(v1.x); a1 += bfhi(v1.x); a2 += bflo(v1.y); a3 += bfhi(v1.y);
      a0 += bflo(v2.x); a1 += bfhi(v2.x); a2 += bflo(v2.y); a3 += bfhi(v2.y);
      a0 += bflo(v3.x); a1 += bfhi(v3.x); a2 += bflo(v3.y); a3 += bfhi(v3.y);
      a0 += bflo(v4.x); a1 += bfhi(v4.x); a2 += bflo(v4.y); a3 += bfhi(v4.y);
      a0 += bflo(v5.x); a1 += bfhi(v5.x); a2 += bflo(v5.y); a3 += bfhi(v5.y);
      a0 += bflo(v6.x); a1 += bfhi(v6.x); a2 += bflo(v6.y); a3 += bfhi(v6.y);
      a0 += bflo(v7.x); a1 += bfhi(v7.x); a2 += bflo(v7.y); a3 += bfhi(v7.y);
    }
    for (; j + 4 <= cnt; j += 4) {
      int s0 = __shfl(idx, j, 32), s1 = __shfl(idx, j + 1, 32);
      int s2 = __shfl(idx, j + 2, 32), s3 = __shfl(idx, j + 3, 32);
      uint2 v0 = hu[(size_t)s0 * 32 + l];
      uint2 v1 = hu[(size_t)s1 * 32 + l];
      uint2 v2 = hu[(size_t)s2 * 32 + l];
      uint2 v3 = hu[(size_t)s3 * 32 + l];
      a0 += bflo(v0.x); a1 += bfhi(v0.x); a2 += bflo(v0.y); a3 += bfhi(v0.y);
      a0 += bflo(v1.x); a1 += bfhi(v1.x); a2 += bflo(v1.y); a3 += bfhi(v1.y);
      a0 += bflo(v2.x); a1 += bfhi(v2.x); a2 += bflo(v2.y); a3 += bfhi(v2.y);
      a0 += bflo(v3.x); a1 += bfhi(v3.x); a2 += bflo(v3.y); a3 += bfhi(v3.y);
    }
    for (; j < cnt; ++j) {
      int s = __shfl(idx, j, 32);
      uint2 v = hu[(size_t)s * 32 + l];
      a0 += bflo(v.x); a1 += bfhi(v.x); a2 += bflo(v.y); a3 += bfhi(v.y);
    }
  }
  unsigned long long o = (unsigned long long)((unsigned int)f2bf(a0) | ((unsigned int)f2bf(a1) << 16)) |
                         ((unsigned long long)((unsigned int)f2bf(a2) | ((unsigned int)f2bf(a3) << 16)) << 32);
  // non-temporal: don't evict gather-hot h rows from L2 for this stream
  __builtin_nontemporal_store(o, (unsigned long long*)zin + (size_t)node * 32 + l);
}

// ---------------- Fused MLP (MFMA): h = relu( relu(zin@W1+b1)@W2 + b2 + h0 ) ----------------
__global__ __launch_bounds__(256) void k_mlp(const unsigned short* __restrict__ zin,
                                             const float* __restrict__ W1g, const float* __restrict__ b1g,
                                             const float* __restrict__ W2g, const float* __restrict__ b2g,
                                             const unsigned short* __restrict__ h0, unsigned short* __restrict__ h) {
  __shared__ unsigned short Wt[128 * 136];
  __shared__ unsigned short zs[64 * 136];
  int tid = threadIdx.x;
  int lane = tid & 63, w = tid >> 6;
  int q = lane >> 4, l16 = lane & 15;
  int n0 = blockIdx.x * 64;

  stage_w(W1g, Wt, tid);

  int row = n0 + w * 16 + l16;
  int rr = (row < N_NODES) ? row : 0;
  bf16x8 afrag[4];
#pragma unroll
  for (int ks = 0; ks < 4; ++ks)
    afrag[ks] = *(bf16x8*)&zin[(size_t)rr * H + ks * 32 + q * 8];

  f32x4 acc[8];
#pragma unroll
  for (int ct = 0; ct < 8; ++ct) acc[ct] = (f32x4){0.f, 0.f, 0.f, 0.f};
  __syncthreads();
#pragma unroll
  for (int ct = 0; ct < 8; ++ct)
#pragma unroll
    for (int ks = 0; ks < 4; ++ks) {
      bf16x8 b = *(bf16x8*)&Wt[(ct * 16 + l16) * 136 + ks * 32 + q * 8];
      acc[ct] = __builtin_amdgcn_mfma_f32_16x16x32_bf16(afrag[ks], b, acc[ct], 0, 0, 0);
    }
  __syncthreads();
  stage_w(W2g, Wt, tid);
#pragma unroll
  for (int ct = 0; ct < 8; ++ct) {
    float bb = b1g[ct * 16 + l16];
#pragma unroll
    for (int r = 0; r < 4; ++r) {
      float v = fmaxf(acc[ct][r] + bb, 0.f);
      zs[(w * 16 + q * 4 + r) * 136 + ct * 16 + l16] = f2bf(v);
    }
  }
  __syncthreads();
  bf16x8 a2[4];
#pragma unroll
  for (int ks = 0; ks < 4; ++ks)
    a2[ks] = *(bf16x8*)&zs[(w * 16 + l16) * 136 + ks * 32 + q * 8];
  f32x4 acc2[8];
#pragma unroll
  for (int ct = 0; ct < 8; ++ct) acc2[ct] = (f32x4){0.f, 0.f, 0.f, 0.f};
#pragma unroll
  for (int ct = 0; ct < 8; ++ct)
#pragma unroll
    for (int ks = 0; ks < 4; ++ks) {
      bf16x8 b = *(bf16x8*)&Wt[(ct * 16 + l16) * 136 + ks * 32 + q * 8];
      acc2[ct] = __builtin_amdgcn_mfma_f32_16x16x32_bf16(a2[ks], b, acc2[ct], 0, 0, 0);
    }
#pragma unroll
  for (int ct = 0; ct < 8; ++ct) {
    float bb = b2g[ct * 16 + l16];
#pragma unroll
    for (int r = 0; r < 4; ++r) {
      float v = acc2[ct][r] + bb;
      zs[(w * 16 + q * 4 + r) * 136 + ct * 16 + l16] = f2bf(v);
    }
  }
  __syncthreads();
  int node = tid >> 2, cb = (tid & 3) * 32;
  if (n0 + node < N_NODES) {
    size_t base = (size_t)(n0 + node) * H + cb;
#pragma unroll
    for (int i = 0; i < 4; ++i) {
      uint4 zv = *(uint4*)&zs[node * 136 + cb + i * 8];
      uint4 hv = *(const uint4*)&h0[base + i * 8];
      unsigned int zr[4] = {zv.x, zv.y, zv.z, zv.w};
      unsigned int hr[4] = {hv.x, hv.y, hv.z, hv.w};
      uint4 o;
      unsigned int orr[4];
#pragma unroll
      for (int j = 0; j < 4; ++j) {
        float a = fmaxf(bflo(zr[j]) + bflo(hr[j]), 0.f);
        float b = fmaxf(bfhi(zr[j]) + bfhi(hr[j]), 0.f);
        orr[j] = (unsigned int)f2bf(a) | ((unsigned int)f2bf(b) << 16);
      }
      o.x = orr[0]; o.y = orr[1]; o.z = orr[2]; o.w = orr[3];
      *(uint4*)&h[base + i * 8] = o;
    }
  }
}

// ---------------- Pooling ----------------
__global__ void k_starts(const int* __restrict__ batch, int* __restrict__ starts) {
  int n = blockIdx.x * 256 + threadIdx.x;
  if (n >= N_NODES) return;
  int b = batch[n];
  if (n == 0) {
    for (int g = 0; g <= b; ++g) starts[g] = 0;
  } else {
    int bp = batch[n - 1];
    for (int g = bp + 1; g <= b; ++g) starts[g] = n;
  }
  if (n == N_NODES - 1) {
    for (int g = b + 1; g <= N_GRAPHS; ++g) starts[g] = N_NODES;
  }
}

__global__ __launch_bounds__(256) void k_pool(const unsigned short* __restrict__ h, const int* __restrict__ starts,
                                              const float* __restrict__ Wf, const float* __restrict__ bf_,
                                              float* __restrict__ out) {
  __shared__ float r[4];
  int g = blockIdx.x, tid = threadIdx.x;
  int lane = tid & 63, w = tid >> 6;
  int beg = starts[g], end = starts[g + 1];
  const unsigned int* hu = (const unsigned int*)h;
  float sx = 0.f, sy = 0.f;
  for (int n = beg + w; n < end; n += 4) {
    unsigned int v = hu[(size_t)n * 64 + lane];
    sx += bflo(v);
    sy += bfhi(v);
  }
  float val = sx * Wf[2 * lane] + sy * Wf[2 * lane + 1];
#pragma unroll
  for (int off = 32; off > 0; off >>= 1) val += __shfl_down(val, off);
  if (lane == 0) r[w] = val;
  __syncthreads();
  if (tid == 0) out[g] = r[0] + r[1] + r[2] + r[3] + bf_[0];
}

extern "C" void kernel_launch(void* const* d_in, const int* in_sizes, int n_in,
                              void* d_out, int out_size, void* d_ws, size_t ws_size,
                              hipStream_t stream) {
  const float* x = (const float*)d_in[0];
  const int* ei = (const int*)d_in[1];
  const int* srcv = ei;
  const int* dstv = ei + N_EDGES;
  const int* batch = (const int*)d_in[3];
  const float* W0 = (const float*)d_in[4];
  const float* b0 = (const float*)d_in[5];
  const float* W1 = (const float*)d_in[6];
  const float* b1 = (const float*)d_in[7];
  const float* W2 = (const float*)d_in[8];
  const float* b2 = (const float*)d_in[9];
  const float* Wf = (const float*)d_in[10];
  const float* bf_ = (const float*)d_in[11];
  float* out = (float*)d_out;

  char* ws = (char*)d_ws;
  size_t o = 0;
  auto alloc = [&](size_t bytes) {
    size_t r = o;
    o = (o + bytes + 255) & ~(size_t)255;
    return r;
  };
  int* offs = (int*)(ws + alloc((N_NODES + 1) * sizeof(int)));
  int* gcnt = (int*)(ws + alloc(NB * sizeof(int)));
  int* boff = (int*)(ws + alloc((NB + 1) * sizeof(int)));
  int* cursor = (int*)(ws + alloc(NB * sizeof(int)));
  unsigned int* ebuf = (unsigned int*)(ws + alloc((size_t)N_EDGES * 4));
  int* csr = (int*)(ws + alloc((size_t)N_EDGES * sizeof(int)));
  int* starts = (int*)(ws + alloc((N_GRAPHS + 1) * sizeof(int)));
  unsigned short* h0 = (unsigned short*)(ws + alloc((size_t)N_NODES * H * 2));
  unsigned short* h = (unsigned short*)(ws + alloc((size_t)N_NODES * H * 2));
  unsigned short* zin = (unsigned short*)(ws + alloc((size_t)N_NODES * H * 2));

  hipMemsetAsync(gcnt, 0, NB * sizeof(int), stream);
  k_bcnt<<<NB, 256, 0, stream>>>(dstv, gcnt);
  k_bscan<<<1, 512, 0, stream>>>(gcnt, boff, cursor);
  k_bucket<<<NB, 256, 0, stream>>>(srcv, dstv, cursor, ebuf);
  k_bsort<<<NB, 256, 0, stream>>>(ebuf, boff, csr, offs);
  k_starts<<<(N_NODES + 255) / 256, 256, 0, stream>>>(batch, starts);

  const int nblk = (N_NODES + 63) / 64;
  k_lin<<<nblk, 256, 0, stream>>>(x, W0, b0, h0);
  for (int i = 0; i < DEPTH; ++i) {
    const unsigned short* hin = (i == 0) ? h0 : h;
    k_agg<<<(N_NODES + 7) / 8, 256, 0, stream>>>(hin, offs, csr, zin);
    k_mlp<<<nblk, 256, 0, stream>>>(zin, W1 + (size_t)i * H * H, b1 + (size_t)i * H,
                                    W2 + (size_t)i * H * H, b2 + (size_t)i * H, h0, h);
  }
  k_pool<<<N_GRAPHS, 256, 0, stream>>>(h, starts, Wf, bf_, out);
}